// Round 9
// baseline (35.455 us; speedup 1.0000x reference)
//
#include <hip/hip_runtime.h>

constexpr int KWIN = 100;
constexpr int HK   = 50;
constexpr int TSUB = 32;    // frames per thread
constexpr int MB   = 8;     // outputs per inner batch (24 f32x2 loads in flight)
constexpr int PB   = 10;    // prime batch

typedef float f32x2 __attribute__((ext_vector_type(2)));

template <bool REFLECT>
__device__ __forceinline__ int tidx(int t) {
    if constexpr (REFLECT) {
        constexpr int T = 16384;
        t = (t < 0) ? -t : t;
        return (t >= T) ? (2 * T - 2 - t) : t;
    }
    return t;   // interior chunk: linear addressing
}

template <bool REFLECT>
__device__ __forceinline__ void run_chunk(
    const f32x2* __restrict__ xb, f32x2* __restrict__ ob, const int t0)
{
    constexpr int Dh = 64;   // f32x2 per frame

    float sx0 = 0.f, sx1 = 0.f, sq0 = 0.f, sq1 = 0.f;

    // ---- prime: window [t0-50, t0+49], 10 batches of 10 vector loads ----
    #pragma unroll
    for (int jb = 0; jb < KWIN; jb += PB) {
        f32x2 g[PB];
        #pragma unroll
        for (int j = 0; j < PB; ++j)
            g[j] = xb[(size_t)tidx<REFLECT>(t0 - HK + jb + j) * Dh];
        #pragma unroll
        for (int j = 0; j < PB; ++j) {
            sx0 += g[j].x; sq0 = fmaf(g[j].x, g[j].x, sq0);
            sx1 += g[j].y; sq1 = fmaf(g[j].y, g[j].y, sq1);
        }
    }

    const float invK   = 1.0f / (float)KWIN;
    const float invKm1 = 1.0f / (float)(KWIN - 1);
    const float fK     = (float)KWIN;

    // ---- main: 32 outputs; per batch issue 24 independent vector loads ----
    #pragma unroll
    for (int tb = 0; tb < TSUB; tb += MB) {
        f32x2 c[MB], o[MB], g[MB];
        #pragma unroll
        for (int j = 0; j < MB; ++j) {
            const int t = t0 + tb + j;
            c[j] = xb[(size_t)t * Dh];                        // x[t]: never reflects
            o[j] = xb[(size_t)tidx<REFLECT>(t - HK) * Dh];    // x[t-50]
            g[j] = xb[(size_t)tidx<REFLECT>(t + HK) * Dh];    // x[t+50]
        }
        #pragma unroll
        for (int j = 0; j < MB; ++j) {
            const float m0 = sx0 * invK;
            const float m1 = sx1 * invK;
            const float va0 = fmaxf((sq0 - fK * m0 * m0) * invKm1, 1e-24f);
            const float va1 = fmaxf((sq1 - fK * m1 * m1) * invKm1, 1e-24f);
            const float r0 = __builtin_amdgcn_rsqf(va0);      // v_rsq_f32
            const float r1 = __builtin_amdgcn_rsqf(va1);
            f32x2 outv;
            outv.x = (c[j].x - m0) * r0;
            outv.y = (c[j].y - m1) * r1;
            // non-temporal: output is never re-read; keep L2/L3 for the
            // read-reuse window instead of 64 MB of dead write data.
            __builtin_nontemporal_store(outv, &ob[(size_t)(t0 + tb + j) * Dh]);
            sx0 += g[j].x - o[j].x;
            sq0 += g[j].x * g[j].x - o[j].x * o[j].x;
            sx1 += g[j].y - o[j].y;
            sq1 += g[j].y * g[j].y - o[j].y * o[j].y;
        }
    }
}

__global__ __launch_bounds__(256, 2) void man_kernel(
    const float* __restrict__ x, float* __restrict__ out)
{
    constexpr int T = 16384;
    constexpr int Dh = 64;

    const int i    = blockIdx.x;                  // 0..1023
    const int bb   = (i & 7) * 128 + (i >> 3);    // XCD (i&7) owns batch b
    const int b    = bb >> 7;                     // 0..7
    const int quad = bb & 127;                    // group of 4 adjacent chunks
    const int w    = threadIdx.x >> 6;            // 0..3 chunk within block
    const int col  = threadIdx.x & 63;            // f32x2 column
    const int t0   = (quad * 4 + w) * TSUB;

    const f32x2* __restrict__ xb =
        reinterpret_cast<const f32x2*>(x) + (size_t)b * T * Dh + col;
    f32x2* __restrict__ ob =
        reinterpret_cast<f32x2*>(out) + (size_t)b * T * Dh + col;

    if (t0 >= HK && t0 + TSUB - 1 + HK < T) {
        run_chunk<false>(xb, ob, t0);
    } else {
        run_chunk<true>(xb, ob, t0);
    }
}

extern "C" void kernel_launch(void* const* d_in, const int* in_sizes, int n_in,
                              void* d_out, int out_size, void* d_ws, size_t ws_size,
                              hipStream_t stream) {
    (void)in_sizes; (void)n_in; (void)d_ws; (void)ws_size; (void)out_size;
    const float* x = (const float*)d_in[0];
    float* out = (float*)d_out;
    // 8 b * 512 chunks * 64 f32x2-cols = 262144 threads = 1024 blocks * 256
    man_kernel<<<dim3(1024), dim3(256), 0, stream>>>(x, out);
}

// Round 10
// 30.263 us; speedup vs baseline: 1.1716x; 1.1716x over previous
//
#include <hip/hip_runtime.h>

constexpr int KWIN = 100;
constexpr int HK   = 50;
constexpr int TSUB = 32;    // frames per thread (4 main batches)
constexpr int MB   = 8;     // outputs per batch -> 24 loads per batch
constexpr int PB   = 20;    // prime batch -> 5 batches

template <bool REFLECT>
__device__ __forceinline__ int tidx(int t) {
    if constexpr (REFLECT) {
        constexpr int T = 16384;
        t = (t < 0) ? -t : t;
        return (t >= T) ? (2 * T - 2 - t) : t;
    }
    return t;   // interior chunk: linear addressing
}

template <bool REFLECT>
__device__ __forceinline__ void load_prime(const float* __restrict__ xb,
                                           const int t0, const int k,
                                           float p[PB]) {
    #pragma unroll
    for (int j = 0; j < PB; ++j)
        p[j] = xb[(size_t)tidx<REFLECT>(t0 - HK + k * PB + j) * 128];
}

__device__ __forceinline__ void acc_prime(const float p[PB],
                                          float& sx, float& sq) {
    #pragma unroll
    for (int j = 0; j < PB; ++j) {
        sx += p[j];
        sq  = fmaf(p[j], p[j], sq);
    }
}

template <bool REFLECT>
__device__ __forceinline__ void load_main(const float* __restrict__ xb,
                                          const int t0, const int tb,
                                          float c[MB], float o[MB], float g[MB]) {
    #pragma unroll
    for (int j = 0; j < MB; ++j) {
        const int t = t0 + tb + j;
        c[j] = xb[(size_t)t * 128];                       // x[t] never reflects
        o[j] = xb[(size_t)tidx<REFLECT>(t - HK) * 128];   // x[t-50]
        g[j] = xb[(size_t)tidx<REFLECT>(t + HK) * 128];   // x[t+50]
    }
}

__device__ __forceinline__ void compute_main(float* __restrict__ ob,
                                             const int t0, const int tb,
                                             const float c[MB], const float o[MB],
                                             const float g[MB],
                                             float& sx, float& sq) {
    const float invK   = 1.0f / (float)KWIN;
    const float invKm1 = 1.0f / (float)(KWIN - 1);
    const float fK     = (float)KWIN;
    #pragma unroll
    for (int j = 0; j < MB; ++j) {
        const float m  = sx * invK;
        const float va = fmaxf((sq - fK * m * m) * invKm1, 1e-24f);
        const float rs = __builtin_amdgcn_rsqf(va);       // v_rsq_f32
        __builtin_nontemporal_store((c[j] - m) * rs,
                                    &ob[(size_t)(t0 + tb + j) * 128]);
        sx += g[j] - o[j];
        sq += g[j] * g[j] - o[j] * o[j];
    }
}

template <bool REFLECT>
__device__ __forceinline__ void run_chunk(
    const float* __restrict__ xb, float* __restrict__ ob, const int t0)
{
    float sx = 0.f, sq = 0.f;

    // ---- prime: 5 batches of 20, software-pipelined 2-deep ----
    float pa[PB], pb_[PB];
    load_prime<REFLECT>(xb, t0, 0, pa);
    load_prime<REFLECT>(xb, t0, 1, pb_);   // batch 1 in flight
    acc_prime(pa, sx, sq);                 // consume batch 0
    load_prime<REFLECT>(xb, t0, 2, pa);
    acc_prime(pb_, sx, sq);
    load_prime<REFLECT>(xb, t0, 3, pb_);
    acc_prime(pa, sx, sq);
    load_prime<REFLECT>(xb, t0, 4, pa);
    acc_prime(pb_, sx, sq);
    acc_prime(pa, sx, sq);

    // ---- main: 4 batches of 8 outputs, software-pipelined 2-deep ----
    float cA[MB], oA[MB], gA[MB], cB[MB], oB[MB], gB[MB];
    load_main<REFLECT>(xb, t0, 0, cA, oA, gA);
    load_main<REFLECT>(xb, t0, 1 * MB, cB, oB, gB);   // batch 1 in flight
    compute_main(ob, t0, 0,      cA, oA, gA, sx, sq); // consume batch 0
    load_main<REFLECT>(xb, t0, 2 * MB, cA, oA, gA);
    compute_main(ob, t0, 1 * MB, cB, oB, gB, sx, sq);
    load_main<REFLECT>(xb, t0, 3 * MB, cB, oB, gB);
    compute_main(ob, t0, 2 * MB, cA, oA, gA, sx, sq);
    compute_main(ob, t0, 3 * MB, cB, oB, gB, sx, sq);
}

__global__ __launch_bounds__(256, 2) void man_kernel(
    const float* __restrict__ x, float* __restrict__ out)
{
    constexpr int T = 16384, D = 128;

    const int i    = blockIdx.x;                  // 0..2047
    const int bb   = (i & 7) * 256 + (i >> 3);    // XCD (i&7) owns batch b
    const int b    = bb >> 8;                     // 0..7
    const int pair = bb & 255;                    // pair of adjacent chunks
    const int w    = threadIdx.x >> 7;            // 0..1 chunk within pair
    const int tid  = threadIdx.x & 127;           // d column
    const int t0   = (pair * 2 + w) * TSUB;

    const float* __restrict__ xb = x   + (size_t)b * T * D + tid;
    float*       __restrict__ ob = out + (size_t)b * T * D + tid;

    if (t0 >= HK && t0 + TSUB - 1 + HK < T) {
        run_chunk<false>(xb, ob, t0);
    } else {
        run_chunk<true>(xb, ob, t0);
    }
}

extern "C" void kernel_launch(void* const* d_in, const int* in_sizes, int n_in,
                              void* d_out, int out_size, void* d_ws, size_t ws_size,
                              hipStream_t stream) {
    (void)in_sizes; (void)n_in; (void)d_ws; (void)ws_size; (void)out_size;
    const float* x = (const float*)d_in[0];
    float* out = (float*)d_out;
    // 8 b * 512 chunks * 128 d = 524288 threads = 2048 blocks * 256
    man_kernel<<<dim3(2048), dim3(256), 0, stream>>>(x, out);
}